// Round 4
// baseline (403.076 us; speedup 1.0000x reference)
//
#include <hip/hip_runtime.h>
#include <math.h>

#define Bb 4
#define Tt 512
#define Uu 128
#define Hh 512
#define Vv 41

typedef __attribute__((ext_vector_type(8))) short short8;
typedef __attribute__((ext_vector_type(4))) float f32x4;
typedef __attribute__((ext_vector_type(2))) float v2f;

// RNE bf16 pack of two floats -> u32 [lo | hi<<16]
__device__ __forceinline__ unsigned pack_bf16_rne(float hi, float lo) {
    unsigned xh = __float_as_uint(hi); xh += 0x7fffu + ((xh >> 16) & 1u);
    unsigned xl = __float_as_uint(lo); xl += 0x7fffu + ((xl >> 16) & 1u);
    return __builtin_amdgcn_perm(xh, xl, 0x07060302);
}

__device__ __forceinline__ unsigned short bf16_rne(float v) {
    unsigned x = __float_as_uint(v);
    x += 0x7fffu + ((x >> 16) & 1u);
    return (unsigned short)(x >> 16);
}

// bf16 pair unpack (u32 = [lo | hi<<16])
__device__ __forceinline__ float bf16lo(unsigned u) { return __uint_as_float(u << 16); }
__device__ __forceinline__ float bf16hi(unsigned u) { return __uint_as_float(u & 0xffff0000u); }

// accurate tanh (err ~1e-6): 1 - 2/(e^{2x}+1); saturates correctly.
__device__ __forceinline__ float tanh_acc(float x) {
    float e = __expf(2.0f * x);
    return 1.0f - 2.0f * __builtin_amdgcn_rcpf(e + 1.0f);
}

// EXACT tanh addition: tanh(s+t) = (ts+tt)/(1+ts*tt).
// PAIR-RECIPROCAL: one v_rcp_f32 per packed pair via 1/d0 = d1*rcp(d0*d1),
// 1/d1 = d0*rcp(d0*d1).  Denominators in (0,2], product in (0,4]: no
// overflow/underflow; extra rel-error ~3ulp, far below bf16 quantization.
__device__ __forceinline__ unsigned mob2p(v2f tt, v2f ts) {
    v2f nm = ts + tt;                     // v_pk_add_f32
    v2f dn = ts * tt + (v2f){1.f, 1.f};   // v_pk_fma_f32
    float r = __builtin_amdgcn_rcpf(dn.x * dn.y);
    v2f q = nm * (v2f){dn.y, dn.x};       // v_pk_mul_f32 (op_sel swap)
    v2f g = q * (v2f){r, r};              // v_pk_mul_f32 (broadcast r)
    return __builtin_amdgcn_perm(__float_as_uint(g.y), __float_as_uint(g.x), 0x07060302);
}

// -------- Prep: blocks 0..135: W1,W2 -> Wp[ntile][kstep][lane][8 bf16];
// Wl -> Wpl3 [kstep][ntile(3)][lane][8 bf16].  Block 135 writes lengths.
// Blocks 136..167: tgt -> A-frag order tgtA[rowtile][kstep][lane][8 bf16].
__global__ __launch_bounds__(256) void prep_pack(
    const float* __restrict__ W1, const float* __restrict__ W2,
    const float* __restrict__ Wl, const float* __restrict__ tgt,
    unsigned short* __restrict__ Wp1, unsigned short* __restrict__ Wp2,
    unsigned short* __restrict__ Wpl3, unsigned short* __restrict__ tgtA,
    const int* __restrict__ sl, const int* __restrict__ tl,
    float* __restrict__ lenDst)
{
    __shared__ __align__(16) char smem[16640];
    const int bid = blockIdx.x, tid = threadIdx.x;

    if (bid >= 136) {   // ---- tgt -> A-frag pack
        unsigned short (*At)[520] = (unsigned short (*)[520])smem;
        const int rt = bid - 136;
        const float4* t4 = (const float4*)(tgt + (size_t)rt * 16 * Hh);
        #pragma unroll
        for (int j = 0; j < 8; ++j) {
            int fi = j * 256 + tid;            // 0..2047
            int row = fi >> 7, c4 = fi & 127;
            float4 v = t4[fi];
            uint2 pk;
            pk.x = pack_bf16_rne(v.y, v.x);
            pk.y = pack_bf16_rne(v.w, v.z);
            *(uint2*)&At[row][c4 * 4] = pk;
        }
        __syncthreads();
        #pragma unroll
        for (int i = 0; i < 4; ++i) {
            int chunk = i * 256 + tid;         // 0..1023
            int ks = chunk >> 6, l = chunk & 63;
            int q = l >> 4, nc = l & 15;
            short8 v = *(const short8*)&At[nc][ks * 32 + q * 8];
            *(short8*)(tgtA + ((size_t)(rt * 16 + ks) * 64 + l) * 8) = v;
        }
        return;
    }

    if (bid == 135 && tid < 2 * Bb)
        lenDst[tid] = (tid < Bb) ? (float)sl[tid] : (float)tl[tid - Bb];

    float (*T)[65] = (float (*)[65])smem;
    const float* Wsrc; unsigned short* Wdst; int k0, n0, isWl;
    if (bid < 64)       { Wsrc = W1; Wdst = Wp1; k0 = (bid >> 3) * 64; n0 = (bid & 7) * 64; isWl = 0; }
    else if (bid < 128) { Wsrc = W2; Wdst = Wp2; k0 = ((bid - 64) >> 3) * 64; n0 = ((bid - 64) & 7) * 64; isWl = 0; }
    else                { Wsrc = Wl; Wdst = Wpl3; k0 = (bid - 128) * 64; n0 = 0; isWl = 1; }

    #pragma unroll
    for (int i = 0; i < 16; ++i) {
        int idx = i * 256 + tid;
        int kk = idx >> 6, nn = idx & 63;
        float v;
        if (isWl) v = (nn < Vv) ? Wl[(k0 + kk) * Vv + nn] : 0.0f;
        else      v = Wsrc[(size_t)(k0 + kk) * 512 + n0 + nn];
        T[kk][nn] = v;
    }
    __syncthreads();

    #pragma unroll
    for (int i = 0; i < 2; ++i) {
        int task = i * 256 + tid;
        int nn = task & 63, kg = task >> 6;
        if (isWl && nn >= 48) continue;
        int n = n0 + nn, k = k0 + kg * 8;
        float e[8];
        #pragma unroll
        for (int j = 0; j < 8; ++j) e[j] = T[kg * 8 + j][nn];
        uint4 pk;
        pk.x = pack_bf16_rne(e[1], e[0]);
        pk.y = pack_bf16_rne(e[3], e[2]);
        pk.z = pack_bf16_rne(e[5], e[4]);
        pk.w = pack_bf16_rne(e[7], e[6]);
        int ntg = n >> 4, ncol = n & 15;
        int ks = (k >> 5) & 15, quad = (k >> 3) & 3;
        int lane = quad * 16 + ncol;
        size_t slot = isWl ? (size_t)((ks * 3 + ntg) * 64 + lane)
                           : (size_t)((ntg * 16 + ks) * 64 + lane);
        *(uint4*)(Wdst + slot * 8) = pk;
    }
}

// -------- Target path, fully fused: tanh(LN(gelu(tgt@W1+b1)@W2+b2)) -> tgtPb.
// 32 blocks x 512 thr (8 waves, wave owns 64 n-cols).  Phase 1: GEMM1 from
// tgtA/Wp1 frags -> GELU -> h1 in LDS.  Phase 2: GEMM2 from LDS A / Wp2 ->
// LN+tanh -> tgtPb bf16 A-frag layout [b][k/8][u][8].
__global__ __launch_bounds__(512) void target_fused(
    const unsigned short* __restrict__ tgtA,
    const unsigned short* __restrict__ Wp1, const float* __restrict__ b1,
    const unsigned short* __restrict__ Wp2, const float* __restrict__ b2,
    const float* __restrict__ ln_g, const float* __restrict__ ln_b,
    unsigned short* __restrict__ tgtPb)
{
    __shared__ unsigned short At[16][520];   // h1 bf16 (1040B stride: 2-way max, free)
    __shared__ float Ct[16][520];

    const int rt = blockIdx.x;               // rows rt*16 .. +16
    const int tid = threadIdx.x, lane = tid & 63, w = tid >> 6;
    const int ncol = lane & 15, quad = lane >> 4;

    const unsigned short* ap = tgtA + ((size_t)rt * 1024 + lane) * 8;
    const unsigned short* bp1 = Wp1 + (size_t)lane * 8 + (size_t)(w * 4) * 8192;
    const unsigned short* bp2 = Wp2 + (size_t)lane * 8 + (size_t)(w * 4) * 8192;

    f32x4 acc[4];
    #pragma unroll
    for (int i = 0; i < 4; ++i) acc[i] = (f32x4){0.f, 0.f, 0.f, 0.f};

    {   // Phase 1: GEMM1 (A global frags, B Wp1), double-buffered
        short8 ac = *(const short8*)(ap);
        short8 bc[4];
        #pragma unroll
        for (int i = 0; i < 4; ++i) bc[i] = *(const short8*)(bp1 + (size_t)i * 8192);
        #pragma unroll
        for (int ks = 0; ks < 16; ++ks) {
            short8 an, bn[4];
            if (ks < 15) {
                an = *(const short8*)(ap + (ks + 1) * 512);
                #pragma unroll
                for (int i = 0; i < 4; ++i)
                    bn[i] = *(const short8*)(bp1 + (size_t)i * 8192 + (ks + 1) * 512);
            }
            #pragma unroll
            for (int i = 0; i < 4; ++i)
                acc[i] = __builtin_amdgcn_mfma_f32_16x16x32_bf16(ac, bc[i], acc[i], 0, 0, 0);
            ac = an;
            #pragma unroll
            for (int i = 0; i < 4; ++i) bc[i] = bn[i];
        }
    }

    // GELU(+b1) -> At
    #pragma unroll
    for (int nt = 0; nt < 4; ++nt) {
        int n = w * 64 + nt * 16 + ncol;
        float bias = b1[n];
        #pragma unroll
        for (int r = 0; r < 4; ++r) {
            float v = acc[nt][r] + bias;
            float g = 0.5f * v * (1.0f + erff(v * 0.70710678118654752f));
            At[quad * 4 + r][n] = bf16_rne(g);
        }
        acc[nt] = (f32x4){0.f, 0.f, 0.f, 0.f};
    }
    __syncthreads();

    {   // Phase 2: GEMM2 (A from LDS, B Wp2), B double-buffered
        short8 bc[4];
        #pragma unroll
        for (int i = 0; i < 4; ++i) bc[i] = *(const short8*)(bp2 + (size_t)i * 8192);
        #pragma unroll
        for (int ks = 0; ks < 16; ++ks) {
            short8 bn[4];
            if (ks < 15) {
                #pragma unroll
                for (int i = 0; i < 4; ++i)
                    bn[i] = *(const short8*)(bp2 + (size_t)i * 8192 + (ks + 1) * 512);
            }
            short8 af = *(const short8*)&At[ncol][ks * 32 + quad * 8];
            #pragma unroll
            for (int i = 0; i < 4; ++i)
                acc[i] = __builtin_amdgcn_mfma_f32_16x16x32_bf16(af, bc[i], acc[i], 0, 0, 0);
            #pragma unroll
            for (int i = 0; i < 4; ++i) bc[i] = bn[i];
        }
    }

    #pragma unroll
    for (int nt = 0; nt < 4; ++nt) {
        int n = w * 64 + nt * 16 + ncol;
        float bias = b2[n];
        #pragma unroll
        for (int r = 0; r < 4; ++r)
            Ct[quad * 4 + r][n] = acc[nt][r] + bias;
    }
    __syncthreads();

    // LayerNorm + tanh: wave w handles rows 2w, 2w+1; write bf16 A-frag layout
    #pragma unroll
    for (int rr = 0; rr < 2; ++rr) {
        const int row = w * 2 + rr;
        const float4* cr = (const float4*)&Ct[row][0];
        float4 v0 = cr[lane], v1 = cr[lane + 64];
        float s = v0.x + v0.y + v0.z + v0.w + v1.x + v1.y + v1.z + v1.w;
        float q = v0.x*v0.x + v0.y*v0.y + v0.z*v0.z + v0.w*v0.w
                + v1.x*v1.x + v1.y*v1.y + v1.z*v1.z + v1.w*v1.w;
        #pragma unroll
        for (int off = 32; off > 0; off >>= 1) {
            s += __shfl_xor(s, off, 64);
            q += __shfl_xor(q, off, 64);
        }
        float mu = s * (1.0f / Hh);
        float rs = rsqrtf(q * (1.0f / Hh) - mu * mu + 1e-5f);

        const int r = rt * 16 + row;
        const int bb = r >> 7, u = r & 127;
        #pragma unroll
        for (int j = 0; j < 2; ++j) {
            int k0 = j * 256 + lane * 4;       // this lane's 4 k-values
            float4 v = j ? v1 : v0;
            float4 g4 = ((const float4*)ln_g)[j * 64 + lane];
            float4 b4 = ((const float4*)ln_b)[j * 64 + lane];
            float4 o;
            o.x = tanh_acc((v.x - mu) * rs * g4.x + b4.x);
            o.y = tanh_acc((v.y - mu) * rs * g4.y + b4.y);
            o.z = tanh_acc((v.z - mu) * rs * g4.z + b4.z);
            o.w = tanh_acc((v.w - mu) * rs * g4.w + b4.w);
            uint2 pk;
            pk.x = pack_bf16_rne(o.y, o.x);
            pk.y = pack_bf16_rne(o.w, o.z);
            int chunk = k0 >> 3, half = (k0 >> 2) & 1;
            *(uint2*)(tgtPb + ((size_t)(bb * 64 + chunk) * 128 + u) * 8 + half * 4) = pk;
        }
    }
}

// -------- Joint: out = tanh(src+tgtP) @ Wl + bl via exact tanh-sum identity.
// R4: OCCUPANCY FIX.  R1 counters: VALU-work model (16 ksteps x ~330 cyc x
// 8 waves/SIMD = 17.6us) matches measured VALUBusy*dur exactly -> the other
// ~26us is idle issue slots from residency: tileC (21KB) capped LDS at 6
// blocks/CU and OccupancyPercent at 31.7%.  Fix: delete the LDS epilogue,
// store acc directly to global (4x64B coalesced segments per store inst,
// writes are fire-and-forget).  LDS 25KB -> 4KB; 8 blocks/CU x 4 waves =
// 32 waves/CU (100%), grid 2048 = exactly one residency round.
// __launch_bounds__(256,8) pins 8 waves/SIMD (VGPR cap 64; uses ~48).
__global__ __launch_bounds__(256, 8) void joint_mfma(
    const float* __restrict__ src, const unsigned short* __restrict__ tgtPb,
    const unsigned short* __restrict__ Wpl3, const float* __restrict__ bl,
    float* __restrict__ out)
{
    __shared__ float srcl[2 * Hh];                       // tanh(src) t0,t1 (4 KB)

    const int t0 = blockIdx.x * 2, b = blockIdx.y, uh = blockIdx.z;
    const int tid = threadIdx.x;
    const int lane = tid & 63, wave = tid >> 6;
    const int ncol = lane & 15, quad = lane >> 4;

    {   // stage tanh(src) for the two rows
        const float4* s4 = (const float4*)(src + ((size_t)(b * Tt + t0)) * Hh);
        float4 v = s4[tid];
        v.x = tanh_acc(v.x); v.y = tanh_acc(v.y);
        v.z = tanh_acc(v.z); v.w = tanh_acc(v.w);
        ((float4*)srcl)[tid] = v;
    }

    const int u0 = uh * 64 + wave * 16 + ncol;   // this wave's 16 u-rows
    // running pointers: A kstep stride 4096 elems, B 1536 elems
    const unsigned short* apl = tgtPb + (size_t)b * 65536 + ((size_t)quad * 128 + u0) * 8;
    const unsigned short* bpl = Wpl3 + (size_t)lane * 8;

    uint4 Aq[2];
    short8 Bq[2][3];
    Aq[0] = *(const uint4*)(apl);
    Bq[0][0] = *(const short8*)(bpl);
    Bq[0][1] = *(const short8*)(bpl + 512);
    Bq[0][2] = *(const short8*)(bpl + 1024);
    apl += 4096; bpl += 1536;
    Aq[1] = *(const uint4*)(apl);
    Bq[1][0] = *(const short8*)(bpl);
    Bq[1][1] = *(const short8*)(bpl + 512);
    Bq[1][2] = *(const short8*)(bpl + 1024);
    apl += 4096; bpl += 1536;

    f32x4 acc[2][3];   // [t][ntile]
    #pragma unroll
    for (int nt = 0; nt < 3; ++nt) {
        int n = nt * 16 + ncol;
        float bv = (n < Vv) ? bl[n] : 0.0f;
        acc[0][nt] = (f32x4){bv, bv, bv, bv};
        acc[1][nt] = (f32x4){bv, bv, bv, bv};
    }

    __syncthreads();
    const float* sr0 = srcl;
    const float* sr1 = srcl + Hh;
    float4 sA0 = *(const float4*)(sr0 + quad * 8);
    float4 sB0 = *(const float4*)(sr0 + quad * 8 + 4);
    float4 sA1 = *(const float4*)(sr1 + quad * 8);
    float4 sB1 = *(const float4*)(sr1 + quad * 8 + 4);

    #pragma unroll
    for (int ks = 0; ks < 16; ++ks) {
        const int st = ks & 1;
        uint4 a = Aq[st];
        short8 B0 = Bq[st][0], B1 = Bq[st][1], B2 = Bq[st][2];

        if (ks + 2 < 16) {   // refill this stage, 2 ksteps ahead
            Aq[st] = *(const uint4*)(apl);
            Bq[st][0] = *(const short8*)(bpl);
            Bq[st][1] = *(const short8*)(bpl + 512);
            Bq[st][2] = *(const short8*)(bpl + 1024);
            apl += 4096; bpl += 1536;
        }
        float4 nsA0, nsB0, nsA1, nsB1;
        if (ks < 15) {
            const int o = (ks + 1) * 32 + quad * 8;
            nsA0 = *(const float4*)(sr0 + o);
            nsB0 = *(const float4*)(sr0 + o + 4);
            nsA1 = *(const float4*)(sr1 + o);
            nsB1 = *(const float4*)(sr1 + o + 4);
        }

        // Pin the pipeline: loads above may not sink below this point,
        // compute below may not hoist above it.
        __builtin_amdgcn_sched_barrier(0);

        // tt unpack hoisted once, shared by the t0 and t1 fragments
        v2f tA = {bf16lo(a.x), bf16hi(a.x)};
        v2f tB = {bf16lo(a.y), bf16hi(a.y)};
        v2f tC = {bf16lo(a.z), bf16hi(a.z)};
        v2f tD = {bf16lo(a.w), bf16hi(a.w)};

        union { uint4 u; short8 s; } f0, f1;
        f0.u.x = mob2p(tA, (v2f){sA0.x, sA0.y});
        f0.u.y = mob2p(tB, (v2f){sA0.z, sA0.w});
        f0.u.z = mob2p(tC, (v2f){sB0.x, sB0.y});
        f0.u.w = mob2p(tD, (v2f){sB0.z, sB0.w});
        f1.u.x = mob2p(tA, (v2f){sA1.x, sA1.y});
        f1.u.y = mob2p(tB, (v2f){sA1.z, sA1.w});
        f1.u.z = mob2p(tC, (v2f){sB1.x, sB1.y});
        f1.u.w = mob2p(tD, (v2f){sB1.z, sB1.w});

        acc[0][0] = __builtin_amdgcn_mfma_f32_16x16x32_bf16(f0.s, B0, acc[0][0], 0, 0, 0);
        acc[1][0] = __builtin_amdgcn_mfma_f32_16x16x32_bf16(f1.s, B0, acc[1][0], 0, 0, 0);
        acc[0][1] = __builtin_amdgcn_mfma_f32_16x16x32_bf16(f0.s, B1, acc[0][1], 0, 0, 0);
        acc[1][1] = __builtin_amdgcn_mfma_f32_16x16x32_bf16(f1.s, B1, acc[1][1], 0, 0, 0);
        acc[0][2] = __builtin_amdgcn_mfma_f32_16x16x32_bf16(f0.s, B2, acc[0][2], 0, 0, 0);
        acc[1][2] = __builtin_amdgcn_mfma_f32_16x16x32_bf16(f1.s, B2, acc[1][2], 0, 0, 0);

        sA0 = nsA0; sB0 = nsB0; sA1 = nsA1; sB1 = nsB1;
    }

    // epilogue: direct global stores from the C-fragment layout
    // (col=lane&15 -> v, row=quad*4+r -> u).  Lanes 0..15 of each quad write
    // a contiguous 64B segment; 4 quads -> 4 rows per store inst.  No LDS,
    // no barriers, stores are fire-and-forget.
    #pragma unroll
    for (int t = 0; t < 2; ++t) {
        float* ob = out + (((size_t)(b * Tt + t0 + t)) * Uu
                           + uh * 64 + wave * 16 + quad * 4) * Vv;
        #pragma unroll
        for (int nt = 0; nt < 3; ++nt) {
            int v = nt * 16 + ncol;
            if (v < Vv) {
                #pragma unroll
                for (int r = 0; r < 4; ++r)
                    ob[r * Vv + v] = acc[t][nt][r];
            }
        }
    }
}

extern "C" void kernel_launch(void* const* d_in, const int* in_sizes, int n_in,
                              void* d_out, int out_size, void* d_ws, size_t ws_size,
                              hipStream_t stream)
{
    const float* src  = (const float*)d_in[0];
    const int*   slen = (const int*)  d_in[1];
    const float* tgt  = (const float*)d_in[2];
    const int*   tlen = (const int*)  d_in[3];
    const float* W1   = (const float*)d_in[4];
    const float* b1   = (const float*)d_in[5];
    const float* W2   = (const float*)d_in[6];
    const float* b2   = (const float*)d_in[7];
    const float* ln_g = (const float*)d_in[8];
    const float* ln_b = (const float*)d_in[9];
    const float* Wl   = (const float*)d_in[10];
    const float* bl   = (const float*)d_in[11];

    float* out = (float*)d_out;
    char* ws = (char*)d_ws;
    // ws: tgtPb bf16 512K | Wp1 512K | Wp2 512K | Wpl3 64K | tgtA 512K
    unsigned short* tgtPb = (unsigned short*)(ws);
    unsigned short* Wp1   = (unsigned short*)(ws + 524288);
    unsigned short* Wp2   = (unsigned short*)(ws + 1048576);
    unsigned short* Wpl3  = (unsigned short*)(ws + 1572864);
    unsigned short* tgtA  = (unsigned short*)(ws + 1638400);

    hipLaunchKernelGGL(prep_pack, dim3(168), dim3(256), 0, stream,
                       W1, W2, Wl, tgt, Wp1, Wp2, Wpl3, tgtA,
                       slen, tlen, out + (size_t)Bb * Tt * Uu * Vv);
    hipLaunchKernelGGL(target_fused, dim3(32), dim3(512), 0, stream,
                       tgtA, Wp1, b1, Wp2, b2, ln_g, ln_b, tgtPb);
    hipLaunchKernelGGL(joint_mfma, dim3(Tt / 2, Bb, 2), dim3(256), 0, stream,
                       src, tgtPb, Wpl3, bl, out);
}

// Round 5
// 134.947 us; speedup vs baseline: 2.9869x; 2.9869x over previous
//
#include <hip/hip_runtime.h>
#include <math.h>

#define Bb 4
#define Tt 512
#define Uu 128
#define Hh 512
#define Vv 41

typedef __attribute__((ext_vector_type(8))) short short8;
typedef __attribute__((ext_vector_type(4))) float f32x4;
typedef __attribute__((ext_vector_type(2))) float v2f;

// RNE bf16 pack of two floats -> u32 [lo | hi<<16]
__device__ __forceinline__ unsigned pack_bf16_rne(float hi, float lo) {
    unsigned xh = __float_as_uint(hi); xh += 0x7fffu + ((xh >> 16) & 1u);
    unsigned xl = __float_as_uint(lo); xl += 0x7fffu + ((xl >> 16) & 1u);
    return __builtin_amdgcn_perm(xh, xl, 0x07060302);
}

__device__ __forceinline__ unsigned short bf16_rne(float v) {
    unsigned x = __float_as_uint(v);
    x += 0x7fffu + ((x >> 16) & 1u);
    return (unsigned short)(x >> 16);
}

// bf16 pair unpack (u32 = [lo | hi<<16])
__device__ __forceinline__ float bf16lo(unsigned u) { return __uint_as_float(u << 16); }
__device__ __forceinline__ float bf16hi(unsigned u) { return __uint_as_float(u & 0xffff0000u); }

// accurate tanh (err ~1e-6): 1 - 2/(e^{2x}+1); saturates correctly.
__device__ __forceinline__ float tanh_acc(float x) {
    float e = __expf(2.0f * x);
    return 1.0f - 2.0f * __builtin_amdgcn_rcpf(e + 1.0f);
}

// EXACT tanh addition: tanh(s+t) = (ts+tt)/(1+ts*tt).
// PAIR-RECIPROCAL: one v_rcp_f32 per packed pair via 1/d0 = d1*rcp(d0*d1),
// 1/d1 = d0*rcp(d0*d1).  Denominators in (0,2], product in (0,4]: no
// overflow/underflow; extra rel-error ~3ulp, far below bf16 quantization.
__device__ __forceinline__ unsigned mob2p(v2f tt, v2f ts) {
    v2f nm = ts + tt;                     // v_pk_add_f32
    v2f dn = ts * tt + (v2f){1.f, 1.f};   // v_pk_fma_f32
    float r = __builtin_amdgcn_rcpf(dn.x * dn.y);
    v2f q = nm * (v2f){dn.y, dn.x};       // v_pk_mul_f32 (op_sel swap)
    v2f g = q * (v2f){r, r};              // v_pk_mul_f32 (broadcast r)
    return __builtin_amdgcn_perm(__float_as_uint(g.y), __float_as_uint(g.x), 0x07060302);
}

// -------- Prep: blocks 0..135: W1,W2 -> Wp[ntile][kstep][lane][8 bf16];
// Wl -> Wpl3 [kstep][ntile(3)][lane][8 bf16].  Block 135 writes lengths.
// Blocks 136..167: tgt -> A-frag order tgtA[rowtile][kstep][lane][8 bf16].
__global__ __launch_bounds__(256) void prep_pack(
    const float* __restrict__ W1, const float* __restrict__ W2,
    const float* __restrict__ Wl, const float* __restrict__ tgt,
    unsigned short* __restrict__ Wp1, unsigned short* __restrict__ Wp2,
    unsigned short* __restrict__ Wpl3, unsigned short* __restrict__ tgtA,
    const int* __restrict__ sl, const int* __restrict__ tl,
    float* __restrict__ lenDst)
{
    __shared__ __align__(16) char smem[16640];
    const int bid = blockIdx.x, tid = threadIdx.x;

    if (bid >= 136) {   // ---- tgt -> A-frag pack
        unsigned short (*At)[520] = (unsigned short (*)[520])smem;
        const int rt = bid - 136;
        const float4* t4 = (const float4*)(tgt + (size_t)rt * 16 * Hh);
        #pragma unroll
        for (int j = 0; j < 8; ++j) {
            int fi = j * 256 + tid;            // 0..2047
            int row = fi >> 7, c4 = fi & 127;
            float4 v = t4[fi];
            uint2 pk;
            pk.x = pack_bf16_rne(v.y, v.x);
            pk.y = pack_bf16_rne(v.w, v.z);
            *(uint2*)&At[row][c4 * 4] = pk;
        }
        __syncthreads();
        #pragma unroll
        for (int i = 0; i < 4; ++i) {
            int chunk = i * 256 + tid;         // 0..1023
            int ks = chunk >> 6, l = chunk & 63;
            int q = l >> 4, nc = l & 15;
            short8 v = *(const short8*)&At[nc][ks * 32 + q * 8];
            *(short8*)(tgtA + ((size_t)(rt * 16 + ks) * 64 + l) * 8) = v;
        }
        return;
    }

    if (bid == 135 && tid < 2 * Bb)
        lenDst[tid] = (tid < Bb) ? (float)sl[tid] : (float)tl[tid - Bb];

    float (*T)[65] = (float (*)[65])smem;
    const float* Wsrc; unsigned short* Wdst; int k0, n0, isWl;
    if (bid < 64)       { Wsrc = W1; Wdst = Wp1; k0 = (bid >> 3) * 64; n0 = (bid & 7) * 64; isWl = 0; }
    else if (bid < 128) { Wsrc = W2; Wdst = Wp2; k0 = ((bid - 64) >> 3) * 64; n0 = ((bid - 64) & 7) * 64; isWl = 0; }
    else                { Wsrc = Wl; Wdst = Wpl3; k0 = (bid - 128) * 64; n0 = 0; isWl = 1; }

    #pragma unroll
    for (int i = 0; i < 16; ++i) {
        int idx = i * 256 + tid;
        int kk = idx >> 6, nn = idx & 63;
        float v;
        if (isWl) v = (nn < Vv) ? Wl[(k0 + kk) * Vv + nn] : 0.0f;
        else      v = Wsrc[(size_t)(k0 + kk) * 512 + n0 + nn];
        T[kk][nn] = v;
    }
    __syncthreads();

    #pragma unroll
    for (int i = 0; i < 2; ++i) {
        int task = i * 256 + tid;
        int nn = task & 63, kg = task >> 6;
        if (isWl && nn >= 48) continue;
        int n = n0 + nn, k = k0 + kg * 8;
        float e[8];
        #pragma unroll
        for (int j = 0; j < 8; ++j) e[j] = T[kg * 8 + j][nn];
        uint4 pk;
        pk.x = pack_bf16_rne(e[1], e[0]);
        pk.y = pack_bf16_rne(e[3], e[2]);
        pk.z = pack_bf16_rne(e[5], e[4]);
        pk.w = pack_bf16_rne(e[7], e[6]);
        int ntg = n >> 4, ncol = n & 15;
        int ks = (k >> 5) & 15, quad = (k >> 3) & 3;
        int lane = quad * 16 + ncol;
        size_t slot = isWl ? (size_t)((ks * 3 + ntg) * 64 + lane)
                           : (size_t)((ntg * 16 + ks) * 64 + lane);
        *(uint4*)(Wdst + slot * 8) = pk;
    }
}

// -------- Target path, fully fused: tanh(LN(gelu(tgt@W1+b1)@W2+b2)) -> tgtPb.
// 32 blocks x 512 thr (8 waves, wave owns 64 n-cols).  Phase 1: GEMM1 from
// tgtA/Wp1 frags -> GELU -> h1 in LDS.  Phase 2: GEMM2 from LDS A / Wp2 ->
// LN+tanh -> tgtPb bf16 A-frag layout [b][k/8][u][8].
__global__ __launch_bounds__(512) void target_fused(
    const unsigned short* __restrict__ tgtA,
    const unsigned short* __restrict__ Wp1, const float* __restrict__ b1,
    const unsigned short* __restrict__ Wp2, const float* __restrict__ b2,
    const float* __restrict__ ln_g, const float* __restrict__ ln_b,
    unsigned short* __restrict__ tgtPb)
{
    __shared__ unsigned short At[16][520];   // h1 bf16 (1040B stride: 2-way max, free)
    __shared__ float Ct[16][520];

    const int rt = blockIdx.x;               // rows rt*16 .. +16
    const int tid = threadIdx.x, lane = tid & 63, w = tid >> 6;
    const int ncol = lane & 15, quad = lane >> 4;

    const unsigned short* ap = tgtA + ((size_t)rt * 1024 + lane) * 8;
    const unsigned short* bp1 = Wp1 + (size_t)lane * 8 + (size_t)(w * 4) * 8192;
    const unsigned short* bp2 = Wp2 + (size_t)lane * 8 + (size_t)(w * 4) * 8192;

    f32x4 acc[4];
    #pragma unroll
    for (int i = 0; i < 4; ++i) acc[i] = (f32x4){0.f, 0.f, 0.f, 0.f};

    {   // Phase 1: GEMM1 (A global frags, B Wp1), double-buffered
        short8 ac = *(const short8*)(ap);
        short8 bc[4];
        #pragma unroll
        for (int i = 0; i < 4; ++i) bc[i] = *(const short8*)(bp1 + (size_t)i * 8192);
        #pragma unroll
        for (int ks = 0; ks < 16; ++ks) {
            short8 an, bn[4];
            if (ks < 15) {
                an = *(const short8*)(ap + (ks + 1) * 512);
                #pragma unroll
                for (int i = 0; i < 4; ++i)
                    bn[i] = *(const short8*)(bp1 + (size_t)i * 8192 + (ks + 1) * 512);
            }
            #pragma unroll
            for (int i = 0; i < 4; ++i)
                acc[i] = __builtin_amdgcn_mfma_f32_16x16x32_bf16(ac, bc[i], acc[i], 0, 0, 0);
            ac = an;
            #pragma unroll
            for (int i = 0; i < 4; ++i) bc[i] = bn[i];
        }
    }

    // GELU(+b1) -> At
    #pragma unroll
    for (int nt = 0; nt < 4; ++nt) {
        int n = w * 64 + nt * 16 + ncol;
        float bias = b1[n];
        #pragma unroll
        for (int r = 0; r < 4; ++r) {
            float v = acc[nt][r] + bias;
            float g = 0.5f * v * (1.0f + erff(v * 0.70710678118654752f));
            At[quad * 4 + r][n] = bf16_rne(g);
        }
        acc[nt] = (f32x4){0.f, 0.f, 0.f, 0.f};
    }
    __syncthreads();

    {   // Phase 2: GEMM2 (A from LDS, B Wp2), B double-buffered
        short8 bc[4];
        #pragma unroll
        for (int i = 0; i < 4; ++i) bc[i] = *(const short8*)(bp2 + (size_t)i * 8192);
        #pragma unroll
        for (int ks = 0; ks < 16; ++ks) {
            short8 bn[4];
            if (ks < 15) {
                #pragma unroll
                for (int i = 0; i < 4; ++i)
                    bn[i] = *(const short8*)(bp2 + (size_t)i * 8192 + (ks + 1) * 512);
            }
            short8 af = *(const short8*)&At[ncol][ks * 32 + quad * 8];
            #pragma unroll
            for (int i = 0; i < 4; ++i)
                acc[i] = __builtin_amdgcn_mfma_f32_16x16x32_bf16(af, bc[i], acc[i], 0, 0, 0);
            #pragma unroll
            for (int i = 0; i < 4; ++i) bc[i] = bn[i];
        }
    }

    #pragma unroll
    for (int nt = 0; nt < 4; ++nt) {
        int n = w * 64 + nt * 16 + ncol;
        float bias = b2[n];
        #pragma unroll
        for (int r = 0; r < 4; ++r)
            Ct[quad * 4 + r][n] = acc[nt][r] + bias;
    }
    __syncthreads();

    // LayerNorm + tanh: wave w handles rows 2w, 2w+1; write bf16 A-frag layout
    #pragma unroll
    for (int rr = 0; rr < 2; ++rr) {
        const int row = w * 2 + rr;
        const float4* cr = (const float4*)&Ct[row][0];
        float4 v0 = cr[lane], v1 = cr[lane + 64];
        float s = v0.x + v0.y + v0.z + v0.w + v1.x + v1.y + v1.z + v1.w;
        float q = v0.x*v0.x + v0.y*v0.y + v0.z*v0.z + v0.w*v0.w
                + v1.x*v1.x + v1.y*v1.y + v1.z*v1.z + v1.w*v1.w;
        #pragma unroll
        for (int off = 32; off > 0; off >>= 1) {
            s += __shfl_xor(s, off, 64);
            q += __shfl_xor(q, off, 64);
        }
        float mu = s * (1.0f / Hh);
        float rs = rsqrtf(q * (1.0f / Hh) - mu * mu + 1e-5f);

        const int r = rt * 16 + row;
        const int bb = r >> 7, u = r & 127;
        #pragma unroll
        for (int j = 0; j < 2; ++j) {
            int k0 = j * 256 + lane * 4;       // this lane's 4 k-values
            float4 v = j ? v1 : v0;
            float4 g4 = ((const float4*)ln_g)[j * 64 + lane];
            float4 b4 = ((const float4*)ln_b)[j * 64 + lane];
            float4 o;
            o.x = tanh_acc((v.x - mu) * rs * g4.x + b4.x);
            o.y = tanh_acc((v.y - mu) * rs * g4.y + b4.y);
            o.z = tanh_acc((v.z - mu) * rs * g4.z + b4.z);
            o.w = tanh_acc((v.w - mu) * rs * g4.w + b4.w);
            uint2 pk;
            pk.x = pack_bf16_rne(o.y, o.x);
            pk.y = pack_bf16_rne(o.w, o.z);
            int chunk = k0 >> 3, half = (k0 >> 2) & 1;
            *(uint2*)(tgtPb + ((size_t)(bb * 64 + chunk) * 128 + u) * 8 + half * 4) = pk;
        }
    }
}

// -------- Joint: out = tanh(src+tgtP) @ Wl + bl via exact tanh-sum identity.
// R5: occupancy fix done RIGHT.  R4 proved the residency lever (Occupancy
// 31.7->66%) but __launch_bounds__(256,8) forced VGPR 48->32 with scratch
// spills (FETCH 4.7MB->481MB) and direct stores caused partial-line RMW.
// This round: KEEP the LDS-staged coalesced epilogue but stage ONE t-tile
// at a time (tileC 21KB -> 10.5KB, two passes).  LDS 25KB -> 14.6KB ->
// 8 blocks/CU (wave-slot-limited), grid 2048 = one full residency round.
// NO min-waves bound: allocator keeps VGPR=48 (<=64 -> 8 waves/SIMD fits).
__global__ __launch_bounds__(256) void joint_mfma(
    const float* __restrict__ src, const unsigned short* __restrict__ tgtPb,
    const unsigned short* __restrict__ Wpl3, const float* __restrict__ bl,
    float* __restrict__ out)
{
    __shared__ float srcl[2 * Hh];                   // tanh(src) t0,t1 (4 KB)
    __shared__ __align__(16) float tileC[64 * Vv];   // 10.25 KB, reused per t

    const int t0 = blockIdx.x * 2, b = blockIdx.y, uh = blockIdx.z;
    const int tid = threadIdx.x;
    const int lane = tid & 63, wave = tid >> 6;
    const int ncol = lane & 15, quad = lane >> 4;

    {   // stage tanh(src) for the two rows
        const float4* s4 = (const float4*)(src + ((size_t)(b * Tt + t0)) * Hh);
        float4 v = s4[tid];
        v.x = tanh_acc(v.x); v.y = tanh_acc(v.y);
        v.z = tanh_acc(v.z); v.w = tanh_acc(v.w);
        ((float4*)srcl)[tid] = v;
    }

    const int u0 = uh * 64 + wave * 16 + ncol;   // this wave's 16 u-rows
    // running pointers: A kstep stride 4096 elems, B 1536 elems
    const unsigned short* apl = tgtPb + (size_t)b * 65536 + ((size_t)quad * 128 + u0) * 8;
    const unsigned short* bpl = Wpl3 + (size_t)lane * 8;

    uint4 Aq[2];
    short8 Bq[2][3];
    Aq[0] = *(const uint4*)(apl);
    Bq[0][0] = *(const short8*)(bpl);
    Bq[0][1] = *(const short8*)(bpl + 512);
    Bq[0][2] = *(const short8*)(bpl + 1024);
    apl += 4096; bpl += 1536;
    Aq[1] = *(const uint4*)(apl);
    Bq[1][0] = *(const short8*)(bpl);
    Bq[1][1] = *(const short8*)(bpl + 512);
    Bq[1][2] = *(const short8*)(bpl + 1024);
    apl += 4096; bpl += 1536;

    f32x4 acc[2][3];   // [t][ntile]
    #pragma unroll
    for (int nt = 0; nt < 3; ++nt) {
        int n = nt * 16 + ncol;
        float bv = (n < Vv) ? bl[n] : 0.0f;
        acc[0][nt] = (f32x4){bv, bv, bv, bv};
        acc[1][nt] = (f32x4){bv, bv, bv, bv};
    }

    __syncthreads();
    const float* sr0 = srcl;
    const float* sr1 = srcl + Hh;
    float4 sA0 = *(const float4*)(sr0 + quad * 8);
    float4 sB0 = *(const float4*)(sr0 + quad * 8 + 4);
    float4 sA1 = *(const float4*)(sr1 + quad * 8);
    float4 sB1 = *(const float4*)(sr1 + quad * 8 + 4);

    #pragma unroll
    for (int ks = 0; ks < 16; ++ks) {
        const int st = ks & 1;
        uint4 a = Aq[st];
        short8 B0 = Bq[st][0], B1 = Bq[st][1], B2 = Bq[st][2];

        if (ks + 2 < 16) {   // refill this stage, 2 ksteps ahead
            Aq[st] = *(const uint4*)(apl);
            Bq[st][0] = *(const short8*)(bpl);
            Bq[st][1] = *(const short8*)(bpl + 512);
            Bq[st][2] = *(const short8*)(bpl + 1024);
            apl += 4096; bpl += 1536;
        }
        float4 nsA0, nsB0, nsA1, nsB1;
        if (ks < 15) {
            const int o = (ks + 1) * 32 + quad * 8;
            nsA0 = *(const float4*)(sr0 + o);
            nsB0 = *(const float4*)(sr0 + o + 4);
            nsA1 = *(const float4*)(sr1 + o);
            nsB1 = *(const float4*)(sr1 + o + 4);
        }

        // Pin the pipeline: loads above may not sink below this point,
        // compute below may not hoist above it.
        __builtin_amdgcn_sched_barrier(0);

        // tt unpack hoisted once, shared by the t0 and t1 fragments
        v2f tA = {bf16lo(a.x), bf16hi(a.x)};
        v2f tB = {bf16lo(a.y), bf16hi(a.y)};
        v2f tC = {bf16lo(a.z), bf16hi(a.z)};
        v2f tD = {bf16lo(a.w), bf16hi(a.w)};

        union { uint4 u; short8 s; } f0, f1;
        f0.u.x = mob2p(tA, (v2f){sA0.x, sA0.y});
        f0.u.y = mob2p(tB, (v2f){sA0.z, sA0.w});
        f0.u.z = mob2p(tC, (v2f){sB0.x, sB0.y});
        f0.u.w = mob2p(tD, (v2f){sB0.z, sB0.w});
        f1.u.x = mob2p(tA, (v2f){sA1.x, sA1.y});
        f1.u.y = mob2p(tB, (v2f){sA1.z, sA1.w});
        f1.u.z = mob2p(tC, (v2f){sB1.x, sB1.y});
        f1.u.w = mob2p(tD, (v2f){sB1.z, sB1.w});

        acc[0][0] = __builtin_amdgcn_mfma_f32_16x16x32_bf16(f0.s, B0, acc[0][0], 0, 0, 0);
        acc[1][0] = __builtin_amdgcn_mfma_f32_16x16x32_bf16(f1.s, B0, acc[1][0], 0, 0, 0);
        acc[0][1] = __builtin_amdgcn_mfma_f32_16x16x32_bf16(f0.s, B1, acc[0][1], 0, 0, 0);
        acc[1][1] = __builtin_amdgcn_mfma_f32_16x16x32_bf16(f1.s, B1, acc[1][1], 0, 0, 0);
        acc[0][2] = __builtin_amdgcn_mfma_f32_16x16x32_bf16(f0.s, B2, acc[0][2], 0, 0, 0);
        acc[1][2] = __builtin_amdgcn_mfma_f32_16x16x32_bf16(f1.s, B2, acc[1][2], 0, 0, 0);

        sA0 = nsA0; sB0 = nsB0; sA1 = nsA1; sB1 = nsB1;
    }

    // epilogue: per t, stage C tile in LDS (C layout col=lane&15,
    // row=quad*4+reg) then contiguous float4 dump.  Two passes over the
    // single-t tileC keep LDS at 10.25 KB.
    #pragma unroll
    for (int t = 0; t < 2; ++t) {
        if (t) __syncthreads();              // pass-0 dump fully read
        #pragma unroll
        for (int nt = 0; nt < 3; ++nt) {
            int n = nt * 16 + ncol;
            if (n < Vv) {
                #pragma unroll
                for (int r = 0; r < 4; ++r)
                    tileC[(wave * 16 + quad * 4 + r) * Vv + n] = acc[t][nt][r];
            }
        }
        __syncthreads();
        float* ob = out + (((size_t)(b * Tt + t0 + t)) * Uu + uh * 64) * Vv;
        const float4* tc4 = (const float4*)tileC;
        #pragma unroll
        for (int i = 0; i < 3; ++i) {
            int idx = i * 256 + tid;          // need 0..655
            if (idx < 656)
                ((float4*)ob)[idx] = tc4[idx];
        }
    }
}

extern "C" void kernel_launch(void* const* d_in, const int* in_sizes, int n_in,
                              void* d_out, int out_size, void* d_ws, size_t ws_size,
                              hipStream_t stream)
{
    const float* src  = (const float*)d_in[0];
    const int*   slen = (const int*)  d_in[1];
    const float* tgt  = (const float*)d_in[2];
    const int*   tlen = (const int*)  d_in[3];
    const float* W1   = (const float*)d_in[4];
    const float* b1   = (const float*)d_in[5];
    const float* W2   = (const float*)d_in[6];
    const float* b2   = (const float*)d_in[7];
    const float* ln_g = (const float*)d_in[8];
    const float* ln_b = (const float*)d_in[9];
    const float* Wl   = (const float*)d_in[10];
    const float* bl   = (const float*)d_in[11];

    float* out = (float*)d_out;
    char* ws = (char*)d_ws;
    // ws: tgtPb bf16 512K | Wp1 512K | Wp2 512K | Wpl3 64K | tgtA 512K
    unsigned short* tgtPb = (unsigned short*)(ws);
    unsigned short* Wp1   = (unsigned short*)(ws + 524288);
    unsigned short* Wp2   = (unsigned short*)(ws + 1048576);
    unsigned short* Wpl3  = (unsigned short*)(ws + 1572864);
    unsigned short* tgtA  = (unsigned short*)(ws + 1638400);

    hipLaunchKernelGGL(prep_pack, dim3(168), dim3(256), 0, stream,
                       W1, W2, Wl, tgt, Wp1, Wp2, Wpl3, tgtA,
                       slen, tlen, out + (size_t)Bb * Tt * Uu * Vv);
    hipLaunchKernelGGL(target_fused, dim3(32), dim3(512), 0, stream,
                       tgtA, Wp1, b1, Wp2, b2, ln_g, ln_b, tgtPb);
    hipLaunchKernelGGL(joint_mfma, dim3(Tt / 2, Bb, 2), dim3(256), 0, stream,
                       src, tgtPb, Wpl3, bl, out);
}